// Round 1
// baseline (653.980 us; speedup 1.0000x reference)
//
#include <hip/hip_runtime.h>

typedef unsigned short u16;
typedef short bf16x8 __attribute__((ext_vector_type(8)));
typedef float f32x4 __attribute__((ext_vector_type(4)));

#define B_ 4
#define S_ 2048
#define D_ 1024
#define H_ 16
#define DH_ 64
#define M_ 8192   // B*S

__device__ __forceinline__ u16 f2b(float f) {
  union { float f; unsigned int u; } v; v.f = f;
  unsigned int u = v.u;
  unsigned int r = (u + 0x7FFFu + ((u >> 16) & 1u)) >> 16;
  return (u16)r;
}

// ---------------- elementwise fp32 -> bf16 ----------------
struct __attribute__((aligned(8))) u16x4 { u16 x, y, z, w; };

__global__ void cvt_f32_bf16(const float* __restrict__ in, u16* __restrict__ out, int n) {
  int i = (blockIdx.x * blockDim.x + threadIdx.x) * 4;
  if (i >= n) return;
  float4 v = *(const float4*)(in + i);
  u16x4 o; o.x = f2b(v.x); o.y = f2b(v.y); o.z = f2b(v.z); o.w = f2b(v.w);
  *(u16x4*)(out + i) = o;
}

// ---------------- tiled transpose + convert: in[R][C] f32 -> out[C][R] bf16 ----------------
__global__ void transpose_cvt(const float* __restrict__ in, u16* __restrict__ out, int R, int C) {
  __shared__ float tile[32][33];
  int c0 = blockIdx.x * 32, r0 = blockIdx.y * 32;
  int tx = threadIdx.x, ty = threadIdx.y; // 32 x 8
#pragma unroll
  for (int j = 0; j < 32; j += 8)
    tile[ty + j][tx] = in[(size_t)(r0 + ty + j) * C + c0 + tx];
  __syncthreads();
#pragma unroll
  for (int j = 0; j < 32; j += 8)
    out[(size_t)(c0 + ty + j) * R + r0 + tx] = f2b(tile[tx][ty + j]);
}

// ---------------- bf16 GEMM: A[M][K] @ BT[N][K]^T + bias ----------------
// MODE 0: write fp32 out[m*Ncols+n]
// MODE 1: qkv scatter into q[B,H,S,Dh], k[B,H,S,Dh], vt[B,H,Dh,S] as bf16
template <int MODE>
__global__ __launch_bounds__(256) void gemm_bt(
    const u16* __restrict__ A, const u16* __restrict__ BT,
    const float* __restrict__ bias, float* __restrict__ outf,
    u16* __restrict__ qb, u16* __restrict__ kb, u16* __restrict__ vtb,
    int Ncols, int Kdim) {
  __shared__ __attribute__((aligned(16))) u16 lsA[128 * 64];
  __shared__ __attribute__((aligned(16))) u16 lsB[128 * 64];
  const int t = threadIdx.x;
  const int lane = t & 63, w = t >> 6;
  const int lhi = lane >> 4, llo = lane & 15;
  const int m0 = blockIdx.y * 128, n0 = blockIdx.x * 128;
  const int wr = (w >> 1) * 64, wc = (w & 1) * 64;

  f32x4 acc[4][4] = {};

  for (int k0 = 0; k0 < Kdim; k0 += 64) {
    // stage A and B tiles: linear global read, XOR-swizzled LDS write
#pragma unroll
    for (int c = 0; c < 4; ++c) {
      int bb = c * 4096 + t * 16;     // dest byte (linear order)
      int row = bb >> 7;              // 128B per row (64 bf16)
      int o = bb & 127;
      int od = o ^ ((row & 7) << 4);  // swizzled byte-col
      bf16x8 va = *(const bf16x8*)(A + (size_t)(m0 + row) * Kdim + k0 + (o >> 1));
      *(bf16x8*)((char*)lsA + row * 128 + od) = va;
      bf16x8 vb = *(const bf16x8*)(BT + (size_t)(n0 + row) * Kdim + k0 + (o >> 1));
      *(bf16x8*)((char*)lsB + row * 128 + od) = vb;
    }
    __syncthreads();
#pragma unroll
    for (int kk = 0; kk < 2; ++kk) {
      bf16x8 af[4], bfr[4];
#pragma unroll
      for (int i = 0; i < 4; ++i) {
        int ra = wr + i * 16 + llo;
        int oa = (kk * 64 + lhi * 16) ^ ((ra & 7) << 4);
        af[i] = *(const bf16x8*)((const char*)lsA + ra * 128 + oa);
        int rb = wc + i * 16 + llo;
        int ob = (kk * 64 + lhi * 16) ^ ((rb & 7) << 4);
        bfr[i] = *(const bf16x8*)((const char*)lsB + rb * 128 + ob);
      }
#pragma unroll
      for (int mi = 0; mi < 4; ++mi)
#pragma unroll
        for (int ni = 0; ni < 4; ++ni)
          acc[mi][ni] = __builtin_amdgcn_mfma_f32_16x16x32_bf16(af[mi], bfr[ni], acc[mi][ni], 0, 0, 0);
    }
    __syncthreads();
  }

  // epilogue: C/D layout row=(lane>>4)*4+r, col=lane&15
#pragma unroll
  for (int mi = 0; mi < 4; ++mi) {
#pragma unroll
    for (int ni = 0; ni < 4; ++ni) {
#pragma unroll
      for (int r = 0; r < 4; ++r) {
        int m = m0 + wr + mi * 16 + lhi * 4 + r;
        int n = n0 + wc + ni * 16 + llo;
        float v = acc[mi][ni][r] + bias[n];
        if (MODE == 0) {
          outf[(size_t)m * Ncols + n] = v;
        } else {
          u16 bv = f2b(v);
          int bidx = m >> 11, s = m & 2047;
          if (n < 1024) {
            int hh = n >> 6, dh = n & 63;
            qb[((size_t)(bidx * 16 + hh) * 2048 + s) * 64 + dh] = bv;
          } else if (n < 2048) {
            int n2 = n - 1024; int hh = n2 >> 6, dh = n2 & 63;
            kb[((size_t)(bidx * 16 + hh) * 2048 + s) * 64 + dh] = bv;
          } else {
            int n2 = n - 2048; int hh = n2 >> 6, dh = n2 & 63;
            vtb[((size_t)(bidx * 16 + hh) * 64 + dh) * 2048 + s] = bv;
          }
        }
      }
    }
  }
}

// ---------------- flash-style causal attention ----------------
// grid: (S/64, B*H), 256 threads (4 waves, 16 q-rows each)
__global__ __launch_bounds__(256) void attn64(
    const u16* __restrict__ Qb, const u16* __restrict__ Kb,
    const u16* __restrict__ VTb, u16* __restrict__ AO) {
  __shared__ __attribute__((aligned(16))) u16 pl[4][16][72]; // per-wave P buffer, +8 pad
  const int t = threadIdx.x, w = t >> 6, lane = t & 63;
  const int lhi = lane >> 4, llo = lane & 15;
  const int bh = blockIdx.y, bb = bh >> 4, hh = bh & 15;
  const int q0 = blockIdx.x * 64;
  const u16* Qp = Qb + (size_t)bh * S_ * DH_;
  const u16* Kp = Kb + (size_t)bh * S_ * DH_;
  const u16* Vp = VTb + (size_t)bh * DH_ * S_;

  const int qrow = q0 + w * 16 + llo;     // A-layout row for this lane
  bf16x8 aq[2];
  aq[0] = *(const bf16x8*)(Qp + (size_t)qrow * DH_ + lhi * 8);
  aq[1] = *(const bf16x8*)(Qp + (size_t)qrow * DH_ + 32 + lhi * 8);

  float mrow[4], lrow[4];
  f32x4 o[4] = {};
#pragma unroll
  for (int r = 0; r < 4; ++r) { mrow[r] = -1e30f; lrow[r] = 0.f; }

  const int crow_base = q0 + w * 16 + lhi * 4; // C-layout row base
  const int ntile = (q0 >> 6) + 1;
  for (int tile = 0; tile < ntile; ++tile) {
    const int kv0 = tile * 64;
    f32x4 sc[4] = {};
#pragma unroll
    for (int kk = 0; kk < 2; ++kk) {
#pragma unroll
      for (int f = 0; f < 4; ++f) {
        bf16x8 bk = *(const bf16x8*)(Kp + (size_t)(kv0 + f * 16 + llo) * DH_ + kk * 32 + lhi * 8);
        sc[f] = __builtin_amdgcn_mfma_f32_16x16x32_bf16(aq[kk], bk, sc[f], 0, 0, 0);
      }
    }
    // scale + causal mask (mask only possible on the diagonal tile)
    float sv[4][4];
    const bool last = (tile == ntile - 1);
#pragma unroll
    for (int f = 0; f < 4; ++f)
#pragma unroll
      for (int r = 0; r < 4; ++r) {
        float x = sc[f][r] * 0.125f;
        if (last) {
          int col = kv0 + f * 16 + llo;
          int row = crow_base + r;
          if (col > row) x = -1e30f;
        }
        sv[f][r] = x;
      }
    // online softmax, wave-parallel (reduce over the 16 llo lanes)
#pragma unroll
    for (int r = 0; r < 4; ++r) {
      float tm = fmaxf(fmaxf(sv[0][r], sv[1][r]), fmaxf(sv[2][r], sv[3][r]));
#pragma unroll
      for (int d = 1; d < 16; d <<= 1) tm = fmaxf(tm, __shfl_xor(tm, d));
      float mn = fmaxf(mrow[r], tm);
      float scr = __expf(mrow[r] - mn);
      mrow[r] = mn;
      float ps = 0.f;
#pragma unroll
      for (int f = 0; f < 4; ++f) {
        float p = __expf(sv[f][r] - mn);
        sv[f][r] = p;
        ps += p;
      }
#pragma unroll
      for (int d = 1; d < 16; d <<= 1) ps += __shfl_xor(ps, d);
      lrow[r] = lrow[r] * scr + ps;
#pragma unroll
      for (int f = 0; f < 4; ++f) o[f][r] *= scr;
#pragma unroll
      for (int f = 0; f < 4; ++f) pl[w][lhi * 4 + r][f * 16 + llo] = f2b(sv[f][r]);
    }
    // PV: A = P (via per-wave LDS redistribute), B = VT (natural layout)
#pragma unroll
    for (int kk = 0; kk < 2; ++kk) {
      bf16x8 ap = *(const bf16x8*)((const char*)&pl[w][llo][0] + kk * 64 + lhi * 16);
#pragma unroll
      for (int f = 0; f < 4; ++f) {
        bf16x8 bv = *(const bf16x8*)(Vp + (size_t)(f * 16 + llo) * S_ + kv0 + kk * 32 + lhi * 8);
        o[f] = __builtin_amdgcn_mfma_f32_16x16x32_bf16(ap, bv, o[f], 0, 0, 0);
      }
    }
  }
  // normalize + write merged-head layout AO[b*S+s][h*64+dh] bf16
#pragma unroll
  for (int f = 0; f < 4; ++f)
#pragma unroll
    for (int r = 0; r < 4; ++r) {
      int row = crow_base + r;
      int dh = f * 16 + llo;
      float val = o[f][r] / lrow[r];
      AO[((size_t)bb * S_ + row) * D_ + hh * DH_ + dh] = f2b(val);
    }
}

extern "C" void kernel_launch(void* const* d_in, const int* in_sizes, int n_in,
                              void* d_out, int out_size, void* d_ws, size_t ws_size,
                              hipStream_t stream) {
  const float* x  = (const float*)d_in[0];
  const float* w1 = (const float*)d_in[1];
  const float* b1 = (const float*)d_in[2];
  const float* w2 = (const float*)d_in[3];
  const float* b2 = (const float*)d_in[4];
  float* out = (float*)d_out;
  char* ws = (char*)d_ws;

  // workspace layout (bytes)
  u16* xb  = (u16*)(ws);                 // 8192x1024 bf16 = 16 MB  (reused as AO after gemm1)
  u16* w1t = (u16*)(ws + 16777216);      // 3072x1024 bf16 = 6 MB
  u16* w2t = (u16*)(ws + 23068672);      // 1024x1024 bf16 = 2 MB
  u16* qb  = (u16*)(ws + 25165824);      // 16 MB
  u16* kb  = (u16*)(ws + 41943040);      // 16 MB
  u16* vtb = (u16*)(ws + 58720256);      // 16 MB
  u16* ao  = xb;                         // alias: x no longer needed after gemm1

  cvt_f32_bf16<<<8192, 256, 0, stream>>>(x, xb, M_ * D_);
  transpose_cvt<<<dim3(96, 32), dim3(32, 8), 0, stream>>>(w1, w1t, 1024, 3072);
  transpose_cvt<<<dim3(32, 32), dim3(32, 8), 0, stream>>>(w2, w2t, 1024, 1024);

  gemm_bt<1><<<dim3(24, 64), 256, 0, stream>>>(xb, w1t, b1, nullptr, qb, kb, vtb, 3072, 1024);
  attn64<<<dim3(32, 64), 256, 0, stream>>>(qb, kb, vtb, ao);
  gemm_bt<0><<<dim3(8, 64), 256, 0, stream>>>(ao, w2t, b2, out, nullptr, nullptr, nullptr, 1024, 1024);
}

// Round 2
// 392.393 us; speedup vs baseline: 1.6666x; 1.6666x over previous
//
#include <hip/hip_runtime.h>

typedef unsigned short u16;
typedef short bf16x8 __attribute__((ext_vector_type(8)));
typedef float f32x4 __attribute__((ext_vector_type(4)));

#define B_ 4
#define S_ 2048
#define D_ 1024
#define H_ 16
#define DH_ 64
#define M_ 8192   // B*S

__device__ __forceinline__ u16 f2b(float f) {
  union { float f; unsigned int u; } v; v.f = f;
  unsigned int u = v.u;
  unsigned int r = (u + 0x7FFFu + ((u >> 16) & 1u)) >> 16;
  return (u16)r;
}

// ---------------- elementwise fp32 -> bf16 ----------------
struct __attribute__((aligned(8))) u16x4 { u16 x, y, z, w; };

__global__ void cvt_f32_bf16(const float* __restrict__ in, u16* __restrict__ out, int n) {
  int i = (blockIdx.x * blockDim.x + threadIdx.x) * 4;
  if (i >= n) return;
  float4 v = *(const float4*)(in + i);
  u16x4 o; o.x = f2b(v.x); o.y = f2b(v.y); o.z = f2b(v.z); o.w = f2b(v.w);
  *(u16x4*)(out + i) = o;
}

// ---------------- tiled transpose + convert: in[R][C] f32 -> out[C][R] bf16 ----------------
__global__ void transpose_cvt(const float* __restrict__ in, u16* __restrict__ out, int R, int C) {
  __shared__ float tile[32][33];
  int c0 = blockIdx.x * 32, r0 = blockIdx.y * 32;
  int tx = threadIdx.x, ty = threadIdx.y; // 32 x 8
#pragma unroll
  for (int j = 0; j < 32; j += 8)
    tile[ty + j][tx] = in[(size_t)(r0 + ty + j) * C + c0 + tx];
  __syncthreads();
#pragma unroll
  for (int j = 0; j < 32; j += 8)
    out[(size_t)(c0 + ty + j) * R + r0 + tx] = f2b(tile[tx][ty + j]);
}

// ---------------- bf16 GEMM: A[M][K] @ BT[N][K]^T + bias ----------------
// MODE 0: write fp32 out[m*Ncols+n]
// MODE 1: qkv scatter into q[B,H,S,Dh], k[B,H,S,Dh], vt[B,H,Dh,S] as bf16
template <int MODE>
__global__ __launch_bounds__(256) void gemm_bt(
    const u16* __restrict__ A, const u16* __restrict__ BT,
    const float* __restrict__ bias, float* __restrict__ outf,
    u16* __restrict__ qb, u16* __restrict__ kb, u16* __restrict__ vtb,
    int Ncols, int Kdim) {
  __shared__ __attribute__((aligned(16))) u16 lsA[128 * 64];
  __shared__ __attribute__((aligned(16))) u16 lsB[128 * 64];
  const int t = threadIdx.x;
  const int lane = t & 63, w = t >> 6;
  const int lhi = lane >> 4, llo = lane & 15;
  const int m0 = blockIdx.y * 128, n0 = blockIdx.x * 128;
  const int wr = (w >> 1) * 64, wc = (w & 1) * 64;

  f32x4 acc[4][4] = {};

  for (int k0 = 0; k0 < Kdim; k0 += 64) {
#pragma unroll
    for (int c = 0; c < 4; ++c) {
      int bb = c * 4096 + t * 16;
      int row = bb >> 7;
      int o = bb & 127;
      int od = o ^ ((row & 7) << 4);
      bf16x8 va = *(const bf16x8*)(A + (size_t)(m0 + row) * Kdim + k0 + (o >> 1));
      *(bf16x8*)((char*)lsA + row * 128 + od) = va;
      bf16x8 vb = *(const bf16x8*)(BT + (size_t)(n0 + row) * Kdim + k0 + (o >> 1));
      *(bf16x8*)((char*)lsB + row * 128 + od) = vb;
    }
    __syncthreads();
#pragma unroll
    for (int kk = 0; kk < 2; ++kk) {
      bf16x8 af[4], bfr[4];
#pragma unroll
      for (int i = 0; i < 4; ++i) {
        int ra = wr + i * 16 + llo;
        int oa = (kk * 64 + lhi * 16) ^ ((ra & 7) << 4);
        af[i] = *(const bf16x8*)((const char*)lsA + ra * 128 + oa);
        int rb = wc + i * 16 + llo;
        int ob = (kk * 64 + lhi * 16) ^ ((rb & 7) << 4);
        bfr[i] = *(const bf16x8*)((const char*)lsB + rb * 128 + ob);
      }
#pragma unroll
      for (int mi = 0; mi < 4; ++mi)
#pragma unroll
        for (int ni = 0; ni < 4; ++ni)
          acc[mi][ni] = __builtin_amdgcn_mfma_f32_16x16x32_bf16(af[mi], bfr[ni], acc[mi][ni], 0, 0, 0);
    }
    __syncthreads();
  }

#pragma unroll
  for (int mi = 0; mi < 4; ++mi) {
#pragma unroll
    for (int ni = 0; ni < 4; ++ni) {
#pragma unroll
      for (int r = 0; r < 4; ++r) {
        int m = m0 + wr + mi * 16 + lhi * 4 + r;
        int n = n0 + wc + ni * 16 + llo;
        float v = acc[mi][ni][r] + bias[n];
        if (MODE == 0) {
          outf[(size_t)m * Ncols + n] = v;
        } else {
          u16 bv = f2b(v);
          int bidx = m >> 11, s = m & 2047;
          if (n < 1024) {
            int hh = n >> 6, dh = n & 63;
            qb[((size_t)(bidx * 16 + hh) * 2048 + s) * 64 + dh] = bv;
          } else if (n < 2048) {
            int n2 = n - 1024; int hh = n2 >> 6, dh = n2 & 63;
            kb[((size_t)(bidx * 16 + hh) * 2048 + s) * 64 + dh] = bv;
          } else {
            int n2 = n - 2048; int hh = n2 >> 6, dh = n2 & 63;
            vtb[((size_t)(bidx * 16 + hh) * 64 + dh) * 2048 + s] = bv;
          }
        }
      }
    }
  }
}

// ---------------- flash-style causal attention, balanced + KVBLK=128 ----------------
// grid: (16, B*H), 256 threads (4 waves, 16 q-rows each).
// block pr handles q-chunks {pr, 31-pr}: every block does exactly 17 kv-128 iterations.
__global__ __launch_bounds__(256) void attn128(
    const u16* __restrict__ Qb, const u16* __restrict__ Kb,
    const u16* __restrict__ VTb, u16* __restrict__ AO) {
  __shared__ __attribute__((aligned(16))) u16 pl[4][16][136]; // per-wave P buffer (+8 pad)
  const int t = threadIdx.x, w = t >> 6, lane = t & 63;
  const int lhi = lane >> 4, llo = lane & 15;
  const int bh = blockIdx.y, bb = bh >> 4, hh = bh & 15;
  const u16* Qp = Qb + (size_t)bh * (S_ * DH_);
  const u16* Kp = Kb + (size_t)bh * (S_ * DH_);
  const u16* Vp = VTb + (size_t)bh * (DH_ * S_);
  const int pr = blockIdx.x;

  for (int ci = 0; ci < 2; ++ci) {
    const int qc = ci ? (31 - pr) : pr;
    const int q0 = qc * 64;
    const int qrow = q0 + w * 16 + llo;
    bf16x8 aq0 = *(const bf16x8*)(Qp + (size_t)qrow * DH_ + lhi * 8);
    bf16x8 aq1 = *(const bf16x8*)(Qp + (size_t)qrow * DH_ + 32 + lhi * 8);

    float mrow[4], lrow[4];
    f32x4 o[4] = {};
#pragma unroll
    for (int r = 0; r < 4; ++r) { mrow[r] = -1e30f; lrow[r] = 0.f; }

    const int crow = q0 + w * 16 + lhi * 4;
    const int n128 = (q0 >> 7) + 1;

    for (int tt = 0; tt < n128; ++tt) {
      const int kv0 = tt << 7;
      // ---- QK^T: 16 MFMAs over 128 kv ----
      f32x4 sc[8] = {};
#pragma unroll
      for (int f = 0; f < 8; ++f) {
        const u16* kp = Kp + (size_t)(kv0 + f * 16 + llo) * DH_ + lhi * 8;
        bf16x8 bk0 = *(const bf16x8*)(kp);
        bf16x8 bk1 = *(const bf16x8*)(kp + 32);
        sc[f] = __builtin_amdgcn_mfma_f32_16x16x32_bf16(aq0, bk0, sc[f], 0, 0, 0);
        sc[f] = __builtin_amdgcn_mfma_f32_16x16x32_bf16(aq1, bk1, sc[f], 0, 0, 0);
      }
      // ---- issue all V loads early: latency hides under softmax ----
      bf16x8 vf[4][4];
#pragma unroll
      for (int f = 0; f < 4; ++f)
#pragma unroll
        for (int kk = 0; kk < 4; ++kk)
          vf[f][kk] = *(const bf16x8*)(Vp + (size_t)(f * 16 + llo) * S_ + kv0 + kk * 32 + lhi * 8);

      const bool lastit = (tt == n128 - 1);
      // ---- online softmax (wave-parallel over 16 llo lanes) ----
#pragma unroll
      for (int r = 0; r < 4; ++r) {
        float tm;
#pragma unroll
        for (int f = 0; f < 8; ++f) {
          float x = sc[f][r] * 0.125f;
          if (lastit && (kv0 + f * 16 + llo > crow + r)) x = -1e30f;
          sc[f][r] = x;
          tm = f ? fmaxf(tm, x) : x;
        }
#pragma unroll
        for (int d = 1; d < 16; d <<= 1) tm = fmaxf(tm, __shfl_xor(tm, d));
        float mn = fmaxf(mrow[r], tm);
        float scr = __expf(mrow[r] - mn);
        mrow[r] = mn;
        float ps = 0.f;
#pragma unroll
        for (int f = 0; f < 8; ++f) {
          float p = __expf(sc[f][r] - mn);
          ps += p;
          pl[w][lhi * 4 + r][f * 16 + llo] = f2b(p);
        }
#pragma unroll
        for (int d = 1; d < 16; d <<= 1) ps += __shfl_xor(ps, d);
        lrow[r] = lrow[r] * scr + ps;
#pragma unroll
        for (int f = 0; f < 4; ++f) o[f][r] *= scr;
      }
      // ---- PV: A = P (per-wave LDS redistribute), B = VT fragments ----
#pragma unroll
      for (int kk = 0; kk < 4; ++kk) {
        bf16x8 ap = *(const bf16x8*)((const char*)&pl[w][llo][0] + kk * 64 + lhi * 16);
#pragma unroll
        for (int f = 0; f < 4; ++f)
          o[f] = __builtin_amdgcn_mfma_f32_16x16x32_bf16(ap, vf[f][kk], o[f], 0, 0, 0);
      }
    }
    // ---- normalize + write merged-head layout ----
#pragma unroll
    for (int f = 0; f < 4; ++f)
#pragma unroll
      for (int r = 0; r < 4; ++r) {
        int row = crow + r;
        int dh = f * 16 + llo;
        float val = o[f][r] / lrow[r];
        AO[((size_t)bb * S_ + row) * D_ + hh * DH_ + dh] = f2b(val);
      }
  }
}

extern "C" void kernel_launch(void* const* d_in, const int* in_sizes, int n_in,
                              void* d_out, int out_size, void* d_ws, size_t ws_size,
                              hipStream_t stream) {
  const float* x  = (const float*)d_in[0];
  const float* w1 = (const float*)d_in[1];
  const float* b1 = (const float*)d_in[2];
  const float* w2 = (const float*)d_in[3];
  const float* b2 = (const float*)d_in[4];
  float* out = (float*)d_out;
  char* ws = (char*)d_ws;

  u16* xb  = (u16*)(ws);                 // 16 MB (reused as AO after gemm1)
  u16* w1t = (u16*)(ws + 16777216);      // 6 MB
  u16* w2t = (u16*)(ws + 23068672);      // 2 MB
  u16* qb  = (u16*)(ws + 25165824);      // 16 MB
  u16* kb  = (u16*)(ws + 41943040);      // 16 MB
  u16* vtb = (u16*)(ws + 58720256);      // 16 MB
  u16* ao  = xb;

  cvt_f32_bf16<<<8192, 256, 0, stream>>>(x, xb, M_ * D_);
  transpose_cvt<<<dim3(96, 32), dim3(32, 8), 0, stream>>>(w1, w1t, 1024, 3072);
  transpose_cvt<<<dim3(32, 32), dim3(32, 8), 0, stream>>>(w2, w2t, 1024, 1024);

  gemm_bt<1><<<dim3(24, 64), 256, 0, stream>>>(xb, w1t, b1, nullptr, qb, kb, vtb, 3072, 1024);
  attn128<<<dim3(16, 64), 256, 0, stream>>>(qb, kb, vtb, ao);
  gemm_bt<0><<<dim3(8, 64), 256, 0, stream>>>(ao, w2t, b2, out, nullptr, nullptr, nullptr, 1024, 1024);
}

// Round 3
// 286.528 us; speedup vs baseline: 2.2824x; 1.3695x over previous
//
#include <hip/hip_runtime.h>

typedef unsigned short u16;
typedef short bf16x8 __attribute__((ext_vector_type(8)));
typedef float f32x4 __attribute__((ext_vector_type(4)));

#define B_ 4
#define S_ 2048
#define D_ 1024
#define H_ 16
#define DH_ 64
#define M_ 8192   // B*S

__device__ __forceinline__ u16 f2b(float f) {
  union { float f; unsigned int u; } v; v.f = f;
  unsigned int u = v.u;
  unsigned int r = (u + 0x7FFFu + ((u >> 16) & 1u)) >> 16;
  return (u16)r;
}

// ---------------- elementwise fp32 -> bf16 ----------------
struct __attribute__((aligned(8))) u16x4 { u16 x, y, z, w; };

__global__ void cvt_f32_bf16(const float* __restrict__ in, u16* __restrict__ out, int n) {
  int i = (blockIdx.x * blockDim.x + threadIdx.x) * 4;
  if (i >= n) return;
  float4 v = *(const float4*)(in + i);
  u16x4 o; o.x = f2b(v.x); o.y = f2b(v.y); o.z = f2b(v.z); o.w = f2b(v.w);
  *(u16x4*)(out + i) = o;
}

// ---------------- tiled transpose + convert: in[R][C] f32 -> out[C][R] bf16 ----------------
__global__ void transpose_cvt(const float* __restrict__ in, u16* __restrict__ out, int R, int C) {
  __shared__ float tile[32][33];
  int c0 = blockIdx.x * 32, r0 = blockIdx.y * 32;
  int tx = threadIdx.x, ty = threadIdx.y; // 32 x 8
#pragma unroll
  for (int j = 0; j < 32; j += 8)
    tile[ty + j][tx] = in[(size_t)(r0 + ty + j) * C + c0 + tx];
  __syncthreads();
#pragma unroll
  for (int j = 0; j < 32; j += 8)
    out[(size_t)(c0 + ty + j) * R + r0 + tx] = f2b(tile[tx][ty + j]);
}

// ---------------- bf16 GEMM: A[M][K] @ BT[N][K]^T + bias ----------------
template <int MODE>
__global__ __launch_bounds__(256) void gemm_bt(
    const u16* __restrict__ A, const u16* __restrict__ BT,
    const float* __restrict__ bias, float* __restrict__ outf,
    u16* __restrict__ qb, u16* __restrict__ kb, u16* __restrict__ vtb,
    int Ncols, int Kdim) {
  __shared__ __attribute__((aligned(16))) u16 lsA[128 * 64];
  __shared__ __attribute__((aligned(16))) u16 lsB[128 * 64];
  const int t = threadIdx.x;
  const int lane = t & 63, w = t >> 6;
  const int lhi = lane >> 4, llo = lane & 15;
  const int m0 = blockIdx.y * 128, n0 = blockIdx.x * 128;
  const int wr = (w >> 1) * 64, wc = (w & 1) * 64;

  f32x4 acc[4][4] = {};

  for (int k0 = 0; k0 < Kdim; k0 += 64) {
#pragma unroll
    for (int c = 0; c < 4; ++c) {
      int bb = c * 4096 + t * 16;
      int row = bb >> 7;
      int o = bb & 127;
      int od = o ^ ((row & 7) << 4);
      bf16x8 va = *(const bf16x8*)(A + (size_t)(m0 + row) * Kdim + k0 + (o >> 1));
      *(bf16x8*)((char*)lsA + row * 128 + od) = va;
      bf16x8 vb = *(const bf16x8*)(BT + (size_t)(n0 + row) * Kdim + k0 + (o >> 1));
      *(bf16x8*)((char*)lsB + row * 128 + od) = vb;
    }
    __syncthreads();
#pragma unroll
    for (int kk = 0; kk < 2; ++kk) {
      bf16x8 af[4], bfr[4];
#pragma unroll
      for (int i = 0; i < 4; ++i) {
        int ra = wr + i * 16 + llo;
        int oa = (kk * 64 + lhi * 16) ^ ((ra & 7) << 4);
        af[i] = *(const bf16x8*)((const char*)lsA + ra * 128 + oa);
        int rb = wc + i * 16 + llo;
        int ob = (kk * 64 + lhi * 16) ^ ((rb & 7) << 4);
        bfr[i] = *(const bf16x8*)((const char*)lsB + rb * 128 + ob);
      }
#pragma unroll
      for (int mi = 0; mi < 4; ++mi)
#pragma unroll
        for (int ni = 0; ni < 4; ++ni)
          acc[mi][ni] = __builtin_amdgcn_mfma_f32_16x16x32_bf16(af[mi], bfr[ni], acc[mi][ni], 0, 0, 0);
    }
    __syncthreads();
  }

#pragma unroll
  for (int mi = 0; mi < 4; ++mi) {
#pragma unroll
    for (int ni = 0; ni < 4; ++ni) {
#pragma unroll
      for (int r = 0; r < 4; ++r) {
        int m = m0 + wr + mi * 16 + lhi * 4 + r;
        int n = n0 + wc + ni * 16 + llo;
        float v = acc[mi][ni][r] + bias[n];
        if (MODE == 0) {
          outf[(size_t)m * Ncols + n] = v;
        } else {
          u16 bv = f2b(v);
          int bidx = m >> 11, s = m & 2047;
          if (n < 1024) {
            int hh = n >> 6, dh = n & 63;
            qb[((size_t)(bidx * 16 + hh) * 2048 + s) * 64 + dh] = bv;
          } else if (n < 2048) {
            int n2 = n - 1024; int hh = n2 >> 6, dh = n2 & 63;
            kb[((size_t)(bidx * 16 + hh) * 2048 + s) * 64 + dh] = bv;
          } else {
            int n2 = n - 2048; int hh = n2 >> 6, dh = n2 & 63;
            vtb[((size_t)(bidx * 16 + hh) * 64 + dh) * 2048 + s] = bv;
          }
        }
      }
    }
  }
}

// ---------------- flash-style causal attention, K double-buffered in LDS ----------------
// grid: (16, B*H), 256 threads (4 waves, 16 q-rows each).
// block pr handles q-chunks {pr, 31-pr}: exactly 17 kv-128 iterations per block.
#define SCL2E 0.1803368801111244f  /* 0.125 * log2(e) */

__global__ __launch_bounds__(256) void attn128(
    const u16* __restrict__ Qb, const u16* __restrict__ Kb,
    const u16* __restrict__ VTb, u16* __restrict__ AO) {
  __shared__ __attribute__((aligned(16))) u16 kls[2][128 * 64]; // swizzled K tiles, 2x16KB
  __shared__ __attribute__((aligned(16))) u16 pl[4][16][136];   // per-wave P buffer (+8 pad)
  const int t = threadIdx.x, w = t >> 6, lane = t & 63;
  const int lhi = lane >> 4, llo = lane & 15;
  const int bh = blockIdx.y, bb = bh >> 4, hh = bh & 15;
  const u16* Qp = Qb + (size_t)bh * (S_ * DH_);
  const u16* Kp = Kb + (size_t)bh * (S_ * DH_);
  const u16* Vp = VTb + (size_t)bh * (DH_ * S_);
  const int pr = blockIdx.x;

  // staging geometry (constant per thread): 4 chunks of 16B, linear over the 16KB tile
  int srow[4], scolB[4], sdst[4];
#pragma unroll
  for (int c = 0; c < 4; ++c) {
    int b = c * 4096 + t * 16;
    srow[c] = b >> 7;                       // kv row within tile
    scolB[c] = (b & 127) >> 1;              // source col (u16 elems)
    sdst[c] = srow[c] * 128 + ((b & 127) ^ ((srow[c] & 7) << 4)); // swizzled dest byte
  }

  for (int ci = 0; ci < 2; ++ci) {
    const int qc = ci ? (31 - pr) : pr;
    const int q0 = qc * 64;
    const int qrow = q0 + w * 16 + llo;
    bf16x8 aq0 = *(const bf16x8*)(Qp + (size_t)qrow * DH_ + lhi * 8);
    bf16x8 aq1 = *(const bf16x8*)(Qp + (size_t)qrow * DH_ + 32 + lhi * 8);
    const int n128 = (q0 >> 7) + 1;

    // prologue: stage K tile 0 into kls[0]
    bf16x8 kst[4];
#pragma unroll
    for (int c = 0; c < 4; ++c)
      kst[c] = *(const bf16x8*)(Kp + (size_t)srow[c] * DH_ + scolB[c]);
    __syncthreads();  // protect previous chunk's readers of kls
#pragma unroll
    for (int c = 0; c < 4; ++c)
      *(bf16x8*)((char*)kls[0] + sdst[c]) = kst[c];
    __syncthreads();

    float mrow[4], lrow[4];
    f32x4 o[4] = {};
#pragma unroll
    for (int r = 0; r < 4; ++r) { mrow[r] = -1e30f; lrow[r] = 0.f; }
    const int crow = q0 + w * 16 + lhi * 4;
    int cur = 0;

    for (int tt = 0; tt < n128; ++tt) {
      const int kv0 = tt << 7;
      const bool pf = (tt + 1 < n128);

      // ---- QK^T from LDS (swizzled ds_read_b128) ----
      f32x4 sc[8] = {};
      const int sw = (llo & 7) << 4;
      __builtin_amdgcn_s_setprio(1);
#pragma unroll
      for (int f = 0; f < 8; ++f) {
        const char* base = (const char*)kls[cur] + (f * 16 + llo) * 128;
        bf16x8 bk0 = *(const bf16x8*)(base + ((lhi * 16) ^ sw));
        bf16x8 bk1 = *(const bf16x8*)(base + ((64 + lhi * 16) ^ sw));
        sc[f] = __builtin_amdgcn_mfma_f32_16x16x32_bf16(aq0, bk0, sc[f], 0, 0, 0);
        sc[f] = __builtin_amdgcn_mfma_f32_16x16x32_bf16(aq1, bk1, sc[f], 0, 0, 0);
      }
      __builtin_amdgcn_s_setprio(0);

      // ---- issue V loads (consumed after softmax ~600cy later) ----
      bf16x8 vf[4][4];
#pragma unroll
      for (int f = 0; f < 4; ++f)
#pragma unroll
        for (int kk = 0; kk < 4; ++kk)
          vf[f][kk] = *(const bf16x8*)(Vp + (size_t)(f * 16 + llo) * S_ + kv0 + kk * 32 + lhi * 8);

      // ---- issue K[t+1] prefetch (consumed at iteration end) ----
      if (pf) {
#pragma unroll
        for (int c = 0; c < 4; ++c)
          kst[c] = *(const bf16x8*)(Kp + (size_t)(kv0 + 128 + srow[c]) * DH_ + scolB[c]);
      }

      // ---- online softmax (exp2 domain, wave-parallel over 16 llo lanes) ----
      const bool lastit = (tt == n128 - 1);
#pragma unroll
      for (int r = 0; r < 4; ++r) {
        float tm;
#pragma unroll
        for (int f = 0; f < 8; ++f) {
          float x = sc[f][r] * SCL2E;
          if (lastit && (kv0 + f * 16 + llo > crow + r)) x = -1e30f;
          sc[f][r] = x;
          tm = f ? fmaxf(tm, x) : x;
        }
#pragma unroll
        for (int d = 1; d < 16; d <<= 1) tm = fmaxf(tm, __shfl_xor(tm, d));
        float mn = fmaxf(mrow[r], tm);
        float scr = exp2f(mrow[r] - mn);
        mrow[r] = mn;
        float ps = 0.f;
#pragma unroll
        for (int f = 0; f < 8; ++f) {
          float p = exp2f(sc[f][r] - mn);
          ps += p;
          pl[w][lhi * 4 + r][f * 16 + llo] = f2b(p);
        }
#pragma unroll
        for (int d = 1; d < 16; d <<= 1) ps += __shfl_xor(ps, d);
        lrow[r] = lrow[r] * scr + ps;
#pragma unroll
        for (int f = 0; f < 4; ++f) o[f][r] *= scr;
      }

      // ---- PV ----
      __builtin_amdgcn_s_setprio(1);
#pragma unroll
      for (int kk = 0; kk < 4; ++kk) {
        bf16x8 ap = *(const bf16x8*)((const char*)&pl[w][llo][0] + kk * 64 + lhi * 16);
#pragma unroll
        for (int f = 0; f < 4; ++f)
          o[f] = __builtin_amdgcn_mfma_f32_16x16x32_bf16(ap, vf[f][kk], o[f], 0, 0, 0);
      }
      __builtin_amdgcn_s_setprio(0);

      // ---- land K[t+1] into the other LDS buffer, publish ----
      if (pf) {
#pragma unroll
        for (int c = 0; c < 4; ++c)
          *(bf16x8*)((char*)kls[cur ^ 1] + sdst[c]) = kst[c];
        __syncthreads();
      }
      cur ^= 1;
    }

    // ---- normalize + write merged-head layout ----
#pragma unroll
    for (int f = 0; f < 4; ++f)
#pragma unroll
      for (int r = 0; r < 4; ++r) {
        int row = crow + r;
        int dh = f * 16 + llo;
        float val = o[f][r] / lrow[r];
        AO[((size_t)bb * S_ + row) * D_ + hh * DH_ + dh] = f2b(val);
      }
  }
}

extern "C" void kernel_launch(void* const* d_in, const int* in_sizes, int n_in,
                              void* d_out, int out_size, void* d_ws, size_t ws_size,
                              hipStream_t stream) {
  const float* x  = (const float*)d_in[0];
  const float* w1 = (const float*)d_in[1];
  const float* b1 = (const float*)d_in[2];
  const float* w2 = (const float*)d_in[3];
  const float* b2 = (const float*)d_in[4];
  float* out = (float*)d_out;
  char* ws = (char*)d_ws;

  u16* xb  = (u16*)(ws);                 // 16 MB (reused as AO after gemm1)
  u16* w1t = (u16*)(ws + 16777216);      // 6 MB
  u16* w2t = (u16*)(ws + 23068672);      // 2 MB
  u16* qb  = (u16*)(ws + 25165824);      // 16 MB
  u16* kb  = (u16*)(ws + 41943040);      // 16 MB
  u16* vtb = (u16*)(ws + 58720256);      // 16 MB
  u16* ao  = xb;

  cvt_f32_bf16<<<8192, 256, 0, stream>>>(x, xb, M_ * D_);
  transpose_cvt<<<dim3(96, 32), dim3(32, 8), 0, stream>>>(w1, w1t, 1024, 3072);
  transpose_cvt<<<dim3(32, 32), dim3(32, 8), 0, stream>>>(w2, w2t, 1024, 1024);

  gemm_bt<1><<<dim3(24, 64), 256, 0, stream>>>(xb, w1t, b1, nullptr, qb, kb, vtb, 3072, 1024);
  attn128<<<dim3(16, 64), 256, 0, stream>>>(qb, kb, vtb, ao);
  gemm_bt<0><<<dim3(8, 64), 256, 0, stream>>>(ao, w2t, b2, out, nullptr, nullptr, nullptr, 1024, 1024);
}